// Round 8
// baseline (108.561 us; speedup 1.0000x reference)
//
#include <hip/hip_runtime.h>
#include <hip/hip_bf16.h>

typedef __attribute__((ext_vector_type(4))) float f32x4;

#define TPB 256

// ---- ws layout (float offsets) ----
#define IN1F   0
#define IN2F   1120
#define HN1F   2240
#define HN2F   4288
#define L1OUT  6336
#define L3OUT  11456
#define GH1    16576
#define GH2    22720
#define GI1    28864
#define GI2    35008
#define H1OFF  41152
#define H2OFF  43200
#define T1OFF  45248
#define T2OFF  49344
// total 53440 floats = 213,760 bytes

// ---- asm load bursts: N back-to-back global_load_dwordx4 + vmcnt(0) inside
// (round-7-verified pattern). global offset imm is 13-bit signed (max 4095),
// so burst5 takes a second base for the 5th load.

__device__ __forceinline__ void burst2(const float* a,
                                       f32x4& w0, f32x4& w1)
{
    asm volatile(
        "global_load_dwordx4 %0, %2, off\n\t"
        "global_load_dwordx4 %1, %2, off offset:1024\n\t"
        "s_waitcnt vmcnt(0)"
        : "=&v"(w0), "=&v"(w1)
        : "v"(a) : "memory");
}

__device__ __forceinline__ void burst4(const float* a,
                                       f32x4& w0, f32x4& w1, f32x4& w2, f32x4& w3)
{
    asm volatile(
        "global_load_dwordx4 %0, %4, off\n\t"
        "global_load_dwordx4 %1, %4, off offset:1024\n\t"
        "global_load_dwordx4 %2, %4, off offset:2048\n\t"
        "global_load_dwordx4 %3, %4, off offset:3072\n\t"
        "s_waitcnt vmcnt(0)"
        : "=&v"(w0), "=&v"(w1), "=&v"(w2), "=&v"(w3)
        : "v"(a) : "memory");
}

__device__ __forceinline__ void burst5(const float* a, const float* a4,
                                       f32x4& w0, f32x4& w1, f32x4& w2,
                                       f32x4& w3, f32x4& w4)
{
    asm volatile(
        "global_load_dwordx4 %0, %5, off\n\t"
        "global_load_dwordx4 %1, %5, off offset:1024\n\t"
        "global_load_dwordx4 %2, %5, off offset:2048\n\t"
        "global_load_dwordx4 %3, %5, off offset:3072\n\t"
        "global_load_dwordx4 %4, %6, off\n\t"
        "s_waitcnt vmcnt(0)"
        : "=&v"(w0), "=&v"(w1), "=&v"(w2), "=&v"(w3), "=&v"(w4)
        : "v"(a), "v"(a4) : "memory");
}

__device__ __forceinline__ float dot4(const f32x4& w, const f32x4& x) {
    return w[0]*x[0] + w[1]*x[1] + w[2]*x[2] + w[3]*x[3];
}

__device__ __forceinline__ float wave_reduce(float acc) {
#pragma unroll
    for (int off = 32; off; off >>= 1) acc += __shfl_xor(acc, off, 64);
    return acc;
}

__device__ __forceinline__ void stage_x(const float* __restrict__ x, float* xl, int K)
{
    for (int i = threadIdx.x; i < (K >> 2); i += TPB)
        ((f32x4*)xl)[i] = ((const f32x4*)x)[i];
    __syncthreads();
}

// ---- ROW-SEQUENTIAL matvecs: whole block sweeps its rows ONE AT A TIME so
// the block presents ONE dense linear read front (r7 showed depth alone is
// not the limiter; this cuts chip-wide concurrent row-streams 12K -> ~2K).

// K=5120: wave w takes quarter [w*1280, w*1280+1280) of the row (5KB, burst5).
template <int ROWS>
__device__ __forceinline__ void mv5120(
    const float* __restrict__ W, const float* __restrict__ bias,
    float* xl, float* red, int row0, float* __restrict__ y, int act)
{
    const int wid  = threadIdx.x >> 6;
    const int lane = threadIdx.x & 63;
    const int c0   = lane * 4;
    const float* xw = xl + wid * 1280 + c0;

#pragma unroll
    for (int r = 0; r < ROWS; ++r) {
        const float* seg = W + (size_t)(row0 + r) * 5120 + wid * 1280 + c0;
        f32x4 w0, w1, w2, w3, w4;
        burst5(seg, seg + 1024, w0, w1, w2, w3, w4);
        float acc = dot4(w0, *reinterpret_cast<const f32x4*>(xw))
                  + dot4(w1, *reinterpret_cast<const f32x4*>(xw + 256))
                  + dot4(w2, *reinterpret_cast<const f32x4*>(xw + 512))
                  + dot4(w3, *reinterpret_cast<const f32x4*>(xw + 768))
                  + dot4(w4, *reinterpret_cast<const f32x4*>(xw + 1024));
        acc = wave_reduce(acc);
        if (lane == 0) red[r * 4 + wid] = acc;
        __syncthreads();   // lockstep: keep all 4 waves on the same row
    }
    if (threadIdx.x < ROWS) {
        int t = threadIdx.x;
        float v = red[t*4] + red[t*4+1] + red[t*4+2] + red[t*4+3] + bias[row0 + t];
        if (act) v = fmaxf(v, 0.f);
        y[row0 + t] = v;
    }
}

// K=2048: wave w takes quarter [w*512, w*512+512) of the row (2KB, burst2).
template <int ROWS>
__device__ __forceinline__ void mv2048(
    const float* __restrict__ W, const float* __restrict__ bias,
    float* xl, float* red, int row0, float* __restrict__ y, int act)
{
    const int wid  = threadIdx.x >> 6;
    const int lane = threadIdx.x & 63;
    const int c0   = lane * 4;
    const float* xw = xl + wid * 512 + c0;

#pragma unroll
    for (int r = 0; r < ROWS; ++r) {
        const float* seg = W + (size_t)(row0 + r) * 2048 + wid * 512 + c0;
        f32x4 w0, w1;
        burst2(seg, w0, w1);
        float acc = dot4(w0, *reinterpret_cast<const f32x4*>(xw))
                  + dot4(w1, *reinterpret_cast<const f32x4*>(xw + 256));
        acc = wave_reduce(acc);
        if (lane == 0) red[r * 4 + wid] = acc;
        __syncthreads();
    }
    if (threadIdx.x < ROWS) {
        int t = threadIdx.x;
        float v = red[t*4] + red[t*4+1] + red[t*4+2] + red[t*4+3] + bias[row0 + t];
        if (act) v = fmaxf(v, 0.f);
        y[row0 + t] = v;
    }
}

// K=4096: wave w takes quarter [w*1024, w*1024+1024) of the row (4KB, burst4).
template <int ROWS>
__device__ __forceinline__ void mv4096(
    const float* __restrict__ W, const float* __restrict__ bias,
    float* xl, float* red, int row0, float* __restrict__ y, int act)
{
    const int wid  = threadIdx.x >> 6;
    const int lane = threadIdx.x & 63;
    const int c0   = lane * 4;
    const float* xw = xl + wid * 1024 + c0;

#pragma unroll
    for (int r = 0; r < ROWS; ++r) {
        const float* seg = W + (size_t)(row0 + r) * 4096 + wid * 1024 + c0;
        f32x4 w0, w1, w2, w3;
        burst4(seg, w0, w1, w2, w3);
        float acc = dot4(w0, *reinterpret_cast<const f32x4*>(xw))
                  + dot4(w1, *reinterpret_cast<const f32x4*>(xw + 256))
                  + dot4(w2, *reinterpret_cast<const f32x4*>(xw + 512))
                  + dot4(w3, *reinterpret_cast<const f32x4*>(xw + 768));
        acc = wave_reduce(acc);
        if (lane == 0) red[r * 4 + wid] = acc;
        __syncthreads();
    }
    if (threadIdx.x < ROWS) {
        int t = threadIdx.x;
        float v = red[t*4] + red[t*4+1] + red[t*4+2] + red[t*4+3] + bias[row0 + t];
        if (act) v = fmaxf(v, 0.f);
        y[row0 + t] = v;
    }
}

// K=1120: wave-per-row (4 consecutive rows = contiguous 17.9KB front),
// burst4 covers 1024 floats, tail 96 floats in plain HIP. ROWS=8 -> 2 steps.
__device__ __forceinline__ void mv1120(
    const float* __restrict__ W, const float* __restrict__ bias,
    float* xl, int row0, float* __restrict__ y, int act)
{
    const int wid  = threadIdx.x >> 6;
    const int lane = threadIdx.x & 63;
    const int c0   = lane * 4;

#pragma unroll
    for (int step = 0; step < 2; ++step) {
        const int rr = row0 + step * 4 + wid;
        const float* Wr = W + (size_t)rr * 1120;
        f32x4 w0, w1, w2, w3;
        burst4(Wr + c0, w0, w1, w2, w3);
        float acc = dot4(w0, *reinterpret_cast<const f32x4*>(xl + c0))
                  + dot4(w1, *reinterpret_cast<const f32x4*>(xl + 256 + c0))
                  + dot4(w2, *reinterpret_cast<const f32x4*>(xl + 512 + c0))
                  + dot4(w3, *reinterpret_cast<const f32x4*>(xl + 768 + c0));
        if (c0 < 96) {
            const f32x4 wt = *reinterpret_cast<const f32x4*>(Wr + 1024 + c0);
            const f32x4 xt = *reinterpret_cast<const f32x4*>(xl + 1024 + c0);
            acc += dot4(wt, xt);
        }
        acc = wave_reduce(acc);
        if (lane == 0) {
            float v = acc + bias[rr];
            if (act) v = fmaxf(v, 0.f);
            y[rr] = v;
        }
    }
}

// ---- stage 0: build input1/input2 + copy hn ----
__global__ void k_prep(const float* __restrict__ state_inno,
                       const float* __restrict__ obs_inno,
                       const float* __restrict__ diff_state,
                       const float* __restrict__ diff_obs,
                       const float* __restrict__ lin_err,
                       const float* __restrict__ jac,
                       const float* __restrict__ hn1,
                       const float* __restrict__ hn2,
                       float* __restrict__ ws)
{
    int i = blockIdx.x * blockDim.x + threadIdx.x;
    if (i < 1120) {
        float v;
        if (i < 32)       v = state_inno[i];
        else if (i < 64)  v = diff_state[i - 32];
        else if (i < 96)  v = lin_err[i - 64];
        else              v = jac[i - 96];
        ws[IN1F + i] = v;
        float v2;
        if (i < 32)       v2 = obs_inno[i];
        else if (i < 64)  v2 = diff_obs[i - 32];
        else              v2 = v;  // lin_err / jacobian shared
        ws[IN2F + i] = v2;
    }
    if (i < 2048) {
        ws[HN1F + i] = hn1[i];
        ws[HN2F + i] = hn2[i];
    }
}

// ---- stage A: l1, l3 (5120x1120, relu) + Whh@hn (6144x2048) x2 ----
// grid = 640 + 640 + 768 + 768 = 2816 (8 rows/block)
__global__ void __launch_bounds__(TPB)
k_stageA(const float* l1_W, const float* l1_b,
         const float* l3_W, const float* l3_b,
         const float* Whh1, const float* bhh1,
         const float* Whh2, const float* bhh2,
         float* ws)
{
    __shared__ float xl[2048];
    __shared__ float red[8 * 4];
    int bid = blockIdx.x;
    if (bid < 640) {
        stage_x(ws + IN1F, xl, 1120);
        mv1120(l1_W, l1_b, xl, bid * 8, ws + L1OUT, 1);
    } else if (bid < 1280) {
        stage_x(ws + IN2F, xl, 1120);
        mv1120(l3_W, l3_b, xl, (bid - 640) * 8, ws + L3OUT, 1);
    } else if (bid < 2048) {
        stage_x(ws + HN1F, xl, 2048);
        mv2048<8>(Whh1, bhh1, xl, red, (bid - 1280) * 8, ws + GH1, 0);
    } else {
        stage_x(ws + HN2F, xl, 2048);
        mv2048<8>(Whh2, bhh2, xl, red, (bid - 2048) * 8, ws + GH2, 0);
    }
}

// ---- stage B: Wih @ l_out (6144x5120) x2 ----
// 6 rows/block: grid = 1024 + 1024 = 2048
__global__ void __launch_bounds__(TPB)
k_stageB(const float* Wih1, const float* bih1,
         const float* Wih2, const float* bih2,
         float* ws)
{
    __shared__ float xl[5120];
    __shared__ float red[6 * 4];
    int bid = blockIdx.x;
    if (bid < 1024) {
        stage_x(ws + L1OUT, xl, 5120);
        mv5120<6>(Wih1, bih1, xl, red, bid * 6, ws + GI1, 0);
    } else {
        stage_x(ws + L3OUT, xl, 5120);
        mv5120<6>(Wih2, bih2, xl, red, (bid - 1024) * 6, ws + GI2, 0);
    }
}

// ---- stage C: GRU gate combine (both branches) ----
__global__ void k_gru(const float* __restrict__ hn1,
                      const float* __restrict__ hn2,
                      float* __restrict__ ws)
{
    int i = blockIdx.x * blockDim.x + threadIdx.x;  // 0..4095
    int b = i >> 11, j = i & 2047;
    const float* gi = ws + (b ? GI2 : GI1);
    const float* gh = ws + (b ? GH2 : GH1);
    const float* hn = b ? hn2 : hn1;
    float r = 1.f / (1.f + expf(-(gi[j] + gh[j])));
    float z = 1.f / (1.f + expf(-(gi[2048 + j] + gh[2048 + j])));
    float n = tanhf(gi[4096 + j] + r * gh[4096 + j]);
    float h = (1.f - z) * n + z * hn[j];
    ws[(b ? H2OFF : H1OFF) + j] = h;
}

// ---- stage D: l2_W1 / l4_W1 (4096x2048, relu). grid = 512 + 512 ----
__global__ void __launch_bounds__(TPB)
k_stageD(const float* W21, const float* b21,
         const float* W41, const float* b41,
         float* ws)
{
    __shared__ float xl[2048];
    __shared__ float red[8 * 4];
    int bid = blockIdx.x;
    if (bid < 512) {
        stage_x(ws + H1OFF, xl, 2048);
        mv2048<8>(W21, b21, xl, red, bid * 8, ws + T1OFF, 1);
    } else {
        stage_x(ws + H2OFF, xl, 2048);
        mv2048<8>(W41, b41, xl, red, (bid - 512) * 8, ws + T2OFF, 1);
    }
}

// ---- stage E: l2_W2 / l4_W2 (1024x4096) -> f32 out. 2 rows/block, grid 1024 ----
__global__ void __launch_bounds__(TPB)
k_stageE(const float* __restrict__ W22, const float* __restrict__ b22,
         const float* __restrict__ W42, const float* __restrict__ b42,
         const float* __restrict__ ws, float* __restrict__ out)
{
    __shared__ float xl[4096];
    __shared__ float red[2 * 4];
    int bid = blockIdx.x;
    if (bid < 512) {
        stage_x(ws + T1OFF, xl, 4096);
        mv4096<2>(W22, b22, xl, red, bid * 2, out, 0);
    } else {
        stage_x(ws + T2OFF, xl, 4096);
        mv4096<2>(W42, b42, xl, red, (bid - 512) * 2, out + 1024, 0);
    }
}

extern "C" void kernel_launch(void* const* d_in, const int* in_sizes, int n_in,
                              void* d_out, int out_size, void* d_ws, size_t ws_size,
                              hipStream_t stream)
{
    const float* state_inno = (const float*)d_in[0];
    const float* obs_inno   = (const float*)d_in[1];
    const float* diff_state = (const float*)d_in[2];
    const float* diff_obs   = (const float*)d_in[3];
    const float* lin_err    = (const float*)d_in[4];
    const float* jac        = (const float*)d_in[5];
    const float* l1_W  = (const float*)d_in[6];
    const float* l1_b  = (const float*)d_in[7];
    const float* g1Wih = (const float*)d_in[8];
    const float* g1Whh = (const float*)d_in[9];
    const float* g1bih = (const float*)d_in[10];
    const float* g1bhh = (const float*)d_in[11];
    const float* l2_W1 = (const float*)d_in[12];
    const float* l2_b1 = (const float*)d_in[13];
    const float* l2_W2 = (const float*)d_in[14];
    const float* l2_b2 = (const float*)d_in[15];
    const float* l3_W  = (const float*)d_in[16];
    const float* l3_b  = (const float*)d_in[17];
    const float* g2Wih = (const float*)d_in[18];
    const float* g2Whh = (const float*)d_in[19];
    const float* g2bih = (const float*)d_in[20];
    const float* g2bhh = (const float*)d_in[21];
    const float* l4_W1 = (const float*)d_in[22];
    const float* l4_b1 = (const float*)d_in[23];
    const float* l4_W2 = (const float*)d_in[24];
    const float* l4_b2 = (const float*)d_in[25];
    const float* hn1   = (const float*)d_in[26];
    const float* hn2   = (const float*)d_in[27];

    float* ws = (float*)d_ws;
    float* out = (float*)d_out;

    hipLaunchKernelGGL(k_prep, dim3(8), dim3(TPB), 0, stream,
                       state_inno, obs_inno, diff_state, diff_obs, lin_err, jac,
                       hn1, hn2, ws);

    hipLaunchKernelGGL(k_stageA, dim3(2816), dim3(TPB), 0, stream,
                       l1_W, l1_b, l3_W, l3_b, g1Whh, g1bhh, g2Whh, g2bhh, ws);

    hipLaunchKernelGGL(k_stageB, dim3(2048), dim3(TPB), 0, stream,
                       g1Wih, g1bih, g2Wih, g2bih, ws);

    hipLaunchKernelGGL(k_gru, dim3(16), dim3(TPB), 0, stream, hn1, hn2, ws);

    hipLaunchKernelGGL(k_stageD, dim3(1024), dim3(TPB), 0, stream,
                       l2_W1, l2_b1, l4_W1, l4_b1, ws);

    hipLaunchKernelGGL(k_stageE, dim3(1024), dim3(TPB), 0, stream,
                       l2_W2, l2_b2, l4_W2, l4_b2, ws, out);
}

// Round 9
// 96.721 us; speedup vs baseline: 1.1224x; 1.1224x over previous
//
#include <hip/hip_runtime.h>
#include <hip/hip_bf16.h>

typedef __attribute__((ext_vector_type(4))) float f32x4;

#define TPB 256

// ---- ws layout (float offsets) ----
#define IN1F   0
#define IN2F   1120
#define HN1F   2240
#define HN2F   4288
#define L1OUT  6336
#define L3OUT  11456
#define GH1    16576
#define GH2    22720
#define GI1    28864
#define GI2    35008
#define H1OFF  41152
#define H2OFF  43200
#define T1OFF  45248
#define T2OFF  49344
// total 53440 floats = 213,760 bytes

// ---- asm load bursts: N back-to-back global_load_dwordx4 + vmcnt(0) inside
// (round-7-verified pattern). global offset imm is 13-bit signed (max 4095),
// so burst5 takes a second base for the 5th load.

__device__ __forceinline__ void burst2(const float* a,
                                       f32x4& w0, f32x4& w1)
{
    asm volatile(
        "global_load_dwordx4 %0, %2, off\n\t"
        "global_load_dwordx4 %1, %2, off offset:1024\n\t"
        "s_waitcnt vmcnt(0)"
        : "=&v"(w0), "=&v"(w1)
        : "v"(a) : "memory");
}

__device__ __forceinline__ void burst4(const float* a,
                                       f32x4& w0, f32x4& w1, f32x4& w2, f32x4& w3)
{
    asm volatile(
        "global_load_dwordx4 %0, %4, off\n\t"
        "global_load_dwordx4 %1, %4, off offset:1024\n\t"
        "global_load_dwordx4 %2, %4, off offset:2048\n\t"
        "global_load_dwordx4 %3, %4, off offset:3072\n\t"
        "s_waitcnt vmcnt(0)"
        : "=&v"(w0), "=&v"(w1), "=&v"(w2), "=&v"(w3)
        : "v"(a) : "memory");
}

// Non-temporal burst: stage B's 252MB stream must NOT allocate in L3.
// This (a) makes B's HBM miss stream dense (vs the ~50%-perforated LRU
// survivor pattern that ran at 1.7 TB/s in rounds 2-8), and (b) stops B
// from evicting the other stages' 246MB, which then fits L3 entirely.
__device__ __forceinline__ void burst5_nt(const float* a, const float* a4,
                                          f32x4& w0, f32x4& w1, f32x4& w2,
                                          f32x4& w3, f32x4& w4)
{
    asm volatile(
        "global_load_dwordx4 %0, %5, off nt\n\t"
        "global_load_dwordx4 %1, %5, off offset:1024 nt\n\t"
        "global_load_dwordx4 %2, %5, off offset:2048 nt\n\t"
        "global_load_dwordx4 %3, %5, off offset:3072 nt\n\t"
        "global_load_dwordx4 %4, %6, off nt\n\t"
        "s_waitcnt vmcnt(0)"
        : "=&v"(w0), "=&v"(w1), "=&v"(w2), "=&v"(w3), "=&v"(w4)
        : "v"(a), "v"(a4) : "memory");
}

__device__ __forceinline__ float dot4(const f32x4& w, const f32x4& x) {
    return w[0]*x[0] + w[1]*x[1] + w[2]*x[2] + w[3]*x[3];
}

__device__ __forceinline__ float wave_reduce(float acc) {
#pragma unroll
    for (int off = 32; off; off >>= 1) acc += __shfl_xor(acc, off, 64);
    return acc;
}

__device__ __forceinline__ void stage_x(const float* __restrict__ x, float* xl, int K)
{
    for (int i = threadIdx.x; i < (K >> 2); i += TPB)
        ((f32x4*)xl)[i] = ((const f32x4*)x)[i];
    __syncthreads();
}

// ---- ROW-SEQUENTIAL matvecs (round-8 structure, passing) ----

// K=5120: wave w takes quarter [w*1280, w*1280+1280) of the row (5KB, burst5_nt).
template <int ROWS>
__device__ __forceinline__ void mv5120(
    const float* __restrict__ W, const float* __restrict__ bias,
    float* xl, float* red, int row0, float* __restrict__ y, int act)
{
    const int wid  = threadIdx.x >> 6;
    const int lane = threadIdx.x & 63;
    const int c0   = lane * 4;
    const float* xw = xl + wid * 1280 + c0;

#pragma unroll
    for (int r = 0; r < ROWS; ++r) {
        const float* seg = W + (size_t)(row0 + r) * 5120 + wid * 1280 + c0;
        f32x4 w0, w1, w2, w3, w4;
        burst5_nt(seg, seg + 1024, w0, w1, w2, w3, w4);
        float acc = dot4(w0, *reinterpret_cast<const f32x4*>(xw))
                  + dot4(w1, *reinterpret_cast<const f32x4*>(xw + 256))
                  + dot4(w2, *reinterpret_cast<const f32x4*>(xw + 512))
                  + dot4(w3, *reinterpret_cast<const f32x4*>(xw + 768))
                  + dot4(w4, *reinterpret_cast<const f32x4*>(xw + 1024));
        acc = wave_reduce(acc);
        if (lane == 0) red[r * 4 + wid] = acc;
        __syncthreads();   // lockstep: keep all 4 waves on the same row
    }
    if (threadIdx.x < ROWS) {
        int t = threadIdx.x;
        float v = red[t*4] + red[t*4+1] + red[t*4+2] + red[t*4+3] + bias[row0 + t];
        if (act) v = fmaxf(v, 0.f);
        y[row0 + t] = v;
    }
}

// K=2048: wave w takes quarter [w*512, w*512+512) of the row (2KB, burst2).
template <int ROWS>
__device__ __forceinline__ void mv2048(
    const float* __restrict__ W, const float* __restrict__ bias,
    float* xl, float* red, int row0, float* __restrict__ y, int act)
{
    const int wid  = threadIdx.x >> 6;
    const int lane = threadIdx.x & 63;
    const int c0   = lane * 4;
    const float* xw = xl + wid * 512 + c0;

#pragma unroll
    for (int r = 0; r < ROWS; ++r) {
        const float* seg = W + (size_t)(row0 + r) * 2048 + wid * 512 + c0;
        f32x4 w0, w1;
        burst2(seg, w0, w1);
        float acc = dot4(w0, *reinterpret_cast<const f32x4*>(xw))
                  + dot4(w1, *reinterpret_cast<const f32x4*>(xw + 256));
        acc = wave_reduce(acc);
        if (lane == 0) red[r * 4 + wid] = acc;
        __syncthreads();
    }
    if (threadIdx.x < ROWS) {
        int t = threadIdx.x;
        float v = red[t*4] + red[t*4+1] + red[t*4+2] + red[t*4+3] + bias[row0 + t];
        if (act) v = fmaxf(v, 0.f);
        y[row0 + t] = v;
    }
}

// K=4096: wave w takes quarter [w*1024, w*1024+1024) of the row (4KB, burst4).
template <int ROWS>
__device__ __forceinline__ void mv4096(
    const float* __restrict__ W, const float* __restrict__ bias,
    float* xl, float* red, int row0, float* __restrict__ y, int act)
{
    const int wid  = threadIdx.x >> 6;
    const int lane = threadIdx.x & 63;
    const int c0   = lane * 4;
    const float* xw = xl + wid * 1024 + c0;

#pragma unroll
    for (int r = 0; r < ROWS; ++r) {
        const float* seg = W + (size_t)(row0 + r) * 4096 + wid * 1024 + c0;
        f32x4 w0, w1, w2, w3;
        burst4(seg, w0, w1, w2, w3);
        float acc = dot4(w0, *reinterpret_cast<const f32x4*>(xw))
                  + dot4(w1, *reinterpret_cast<const f32x4*>(xw + 256))
                  + dot4(w2, *reinterpret_cast<const f32x4*>(xw + 512))
                  + dot4(w3, *reinterpret_cast<const f32x4*>(xw + 768));
        acc = wave_reduce(acc);
        if (lane == 0) red[r * 4 + wid] = acc;
        __syncthreads();
    }
    if (threadIdx.x < ROWS) {
        int t = threadIdx.x;
        float v = red[t*4] + red[t*4+1] + red[t*4+2] + red[t*4+3] + bias[row0 + t];
        if (act) v = fmaxf(v, 0.f);
        y[row0 + t] = v;
    }
}

// K=1120: wave-per-row (4 consecutive rows = contiguous 17.9KB front),
// burst4 covers 1024 floats, tail 96 floats in plain HIP. ROWS=8 -> 2 steps.
__device__ __forceinline__ void mv1120(
    const float* __restrict__ W, const float* __restrict__ bias,
    float* xl, int row0, float* __restrict__ y, int act)
{
    const int wid  = threadIdx.x >> 6;
    const int lane = threadIdx.x & 63;
    const int c0   = lane * 4;

#pragma unroll
    for (int step = 0; step < 2; ++step) {
        const int rr = row0 + step * 4 + wid;
        const float* Wr = W + (size_t)rr * 1120;
        f32x4 w0, w1, w2, w3;
        burst4(Wr + c0, w0, w1, w2, w3);
        float acc = dot4(w0, *reinterpret_cast<const f32x4*>(xl + c0))
                  + dot4(w1, *reinterpret_cast<const f32x4*>(xl + 256 + c0))
                  + dot4(w2, *reinterpret_cast<const f32x4*>(xl + 512 + c0))
                  + dot4(w3, *reinterpret_cast<const f32x4*>(xl + 768 + c0));
        if (c0 < 96) {
            const f32x4 wt = *reinterpret_cast<const f32x4*>(Wr + 1024 + c0);
            const f32x4 xt = *reinterpret_cast<const f32x4*>(xl + 1024 + c0);
            acc += dot4(wt, xt);
        }
        acc = wave_reduce(acc);
        if (lane == 0) {
            float v = acc + bias[rr];
            if (act) v = fmaxf(v, 0.f);
            y[rr] = v;
        }
    }
}

// ---- stage 0: build input1/input2 + copy hn ----
__global__ void k_prep(const float* __restrict__ state_inno,
                       const float* __restrict__ obs_inno,
                       const float* __restrict__ diff_state,
                       const float* __restrict__ diff_obs,
                       const float* __restrict__ lin_err,
                       const float* __restrict__ jac,
                       const float* __restrict__ hn1,
                       const float* __restrict__ hn2,
                       float* __restrict__ ws)
{
    int i = blockIdx.x * blockDim.x + threadIdx.x;
    if (i < 1120) {
        float v;
        if (i < 32)       v = state_inno[i];
        else if (i < 64)  v = diff_state[i - 32];
        else if (i < 96)  v = lin_err[i - 64];
        else              v = jac[i - 96];
        ws[IN1F + i] = v;
        float v2;
        if (i < 32)       v2 = obs_inno[i];
        else if (i < 64)  v2 = diff_obs[i - 32];
        else              v2 = v;  // lin_err / jacobian shared
        ws[IN2F + i] = v2;
    }
    if (i < 2048) {
        ws[HN1F + i] = hn1[i];
        ws[HN2F + i] = hn2[i];
    }
}

// ---- stage A: l1, l3 (5120x1120, relu) + Whh@hn (6144x2048) x2 ----
// grid = 640 + 640 + 768 + 768 = 2816 (8 rows/block)
__global__ void __launch_bounds__(TPB)
k_stageA(const float* l1_W, const float* l1_b,
         const float* l3_W, const float* l3_b,
         const float* Whh1, const float* bhh1,
         const float* Whh2, const float* bhh2,
         float* ws)
{
    __shared__ float xl[2048];
    __shared__ float red[8 * 4];
    int bid = blockIdx.x;
    if (bid < 640) {
        stage_x(ws + IN1F, xl, 1120);
        mv1120(l1_W, l1_b, xl, bid * 8, ws + L1OUT, 1);
    } else if (bid < 1280) {
        stage_x(ws + IN2F, xl, 1120);
        mv1120(l3_W, l3_b, xl, (bid - 640) * 8, ws + L3OUT, 1);
    } else if (bid < 2048) {
        stage_x(ws + HN1F, xl, 2048);
        mv2048<8>(Whh1, bhh1, xl, red, (bid - 1280) * 8, ws + GH1, 0);
    } else {
        stage_x(ws + HN2F, xl, 2048);
        mv2048<8>(Whh2, bhh2, xl, red, (bid - 2048) * 8, ws + GH2, 0);
    }
}

// ---- stage B: Wih @ l_out (6144x5120) x2, non-temporal weight reads ----
// 6 rows/block: grid = 1024 + 1024 = 2048
__global__ void __launch_bounds__(TPB)
k_stageB(const float* Wih1, const float* bih1,
         const float* Wih2, const float* bih2,
         float* ws)
{
    __shared__ float xl[5120];
    __shared__ float red[6 * 4];
    int bid = blockIdx.x;
    if (bid < 1024) {
        stage_x(ws + L1OUT, xl, 5120);
        mv5120<6>(Wih1, bih1, xl, red, bid * 6, ws + GI1, 0);
    } else {
        stage_x(ws + L3OUT, xl, 5120);
        mv5120<6>(Wih2, bih2, xl, red, (bid - 1024) * 6, ws + GI2, 0);
    }
}

// ---- stage C: GRU gate combine (both branches) ----
__global__ void k_gru(const float* __restrict__ hn1,
                      const float* __restrict__ hn2,
                      float* __restrict__ ws)
{
    int i = blockIdx.x * blockDim.x + threadIdx.x;  // 0..4095
    int b = i >> 11, j = i & 2047;
    const float* gi = ws + (b ? GI2 : GI1);
    const float* gh = ws + (b ? GH2 : GH1);
    const float* hn = b ? hn2 : hn1;
    float r = 1.f / (1.f + expf(-(gi[j] + gh[j])));
    float z = 1.f / (1.f + expf(-(gi[2048 + j] + gh[2048 + j])));
    float n = tanhf(gi[4096 + j] + r * gh[4096 + j]);
    float h = (1.f - z) * n + z * hn[j];
    ws[(b ? H2OFF : H1OFF) + j] = h;
}

// ---- stage D: l2_W1 / l4_W1 (4096x2048, relu). grid = 512 + 512 ----
__global__ void __launch_bounds__(TPB)
k_stageD(const float* W21, const float* b21,
         const float* W41, const float* b41,
         float* ws)
{
    __shared__ float xl[2048];
    __shared__ float red[8 * 4];
    int bid = blockIdx.x;
    if (bid < 512) {
        stage_x(ws + H1OFF, xl, 2048);
        mv2048<8>(W21, b21, xl, red, bid * 8, ws + T1OFF, 1);
    } else {
        stage_x(ws + H2OFF, xl, 2048);
        mv2048<8>(W41, b41, xl, red, (bid - 512) * 8, ws + T2OFF, 1);
    }
}

// ---- stage E: l2_W2 / l4_W2 (1024x4096) -> f32 out. 2 rows/block, grid 1024 ----
__global__ void __launch_bounds__(TPB)
k_stageE(const float* __restrict__ W22, const float* __restrict__ b22,
         const float* __restrict__ W42, const float* __restrict__ b42,
         const float* __restrict__ ws, float* __restrict__ out)
{
    __shared__ float xl[4096];
    __shared__ float red[2 * 4];
    int bid = blockIdx.x;
    if (bid < 512) {
        stage_x(ws + T1OFF, xl, 4096);
        mv4096<2>(W22, b22, xl, red, bid * 2, out, 0);
    } else {
        stage_x(ws + T2OFF, xl, 4096);
        mv4096<2>(W42, b42, xl, red, (bid - 512) * 2, out + 1024, 0);
    }
}

extern "C" void kernel_launch(void* const* d_in, const int* in_sizes, int n_in,
                              void* d_out, int out_size, void* d_ws, size_t ws_size,
                              hipStream_t stream)
{
    const float* state_inno = (const float*)d_in[0];
    const float* obs_inno   = (const float*)d_in[1];
    const float* diff_state = (const float*)d_in[2];
    const float* diff_obs   = (const float*)d_in[3];
    const float* lin_err    = (const float*)d_in[4];
    const float* jac        = (const float*)d_in[5];
    const float* l1_W  = (const float*)d_in[6];
    const float* l1_b  = (const float*)d_in[7];
    const float* g1Wih = (const float*)d_in[8];
    const float* g1Whh = (const float*)d_in[9];
    const float* g1bih = (const float*)d_in[10];
    const float* g1bhh = (const float*)d_in[11];
    const float* l2_W1 = (const float*)d_in[12];
    const float* l2_b1 = (const float*)d_in[13];
    const float* l2_W2 = (const float*)d_in[14];
    const float* l2_b2 = (const float*)d_in[15];
    const float* l3_W  = (const float*)d_in[16];
    const float* l3_b  = (const float*)d_in[17];
    const float* g2Wih = (const float*)d_in[18];
    const float* g2Whh = (const float*)d_in[19];
    const float* g2bih = (const float*)d_in[20];
    const float* g2bhh = (const float*)d_in[21];
    const float* l4_W1 = (const float*)d_in[22];
    const float* l4_b1 = (const float*)d_in[23];
    const float* l4_W2 = (const float*)d_in[24];
    const float* l4_b2 = (const float*)d_in[25];
    const float* hn1   = (const float*)d_in[26];
    const float* hn2   = (const float*)d_in[27];

    float* ws = (float*)d_ws;
    float* out = (float*)d_out;

    hipLaunchKernelGGL(k_prep, dim3(8), dim3(TPB), 0, stream,
                       state_inno, obs_inno, diff_state, diff_obs, lin_err, jac,
                       hn1, hn2, ws);

    hipLaunchKernelGGL(k_stageA, dim3(2816), dim3(TPB), 0, stream,
                       l1_W, l1_b, l3_W, l3_b, g1Whh, g1bhh, g2Whh, g2bhh, ws);

    hipLaunchKernelGGL(k_stageB, dim3(2048), dim3(TPB), 0, stream,
                       g1Wih, g1bih, g2Wih, g2bih, ws);

    hipLaunchKernelGGL(k_gru, dim3(16), dim3(TPB), 0, stream, hn1, hn2, ws);

    hipLaunchKernelGGL(k_stageD, dim3(1024), dim3(TPB), 0, stream,
                       l2_W1, l2_b1, l4_W1, l4_b1, ws);

    hipLaunchKernelGGL(k_stageE, dim3(1024), dim3(TPB), 0, stream,
                       l2_W2, l2_b2, l4_W2, l4_b2, ws, out);
}